// Round 1
// baseline (17251.859 us; speedup 1.0000x reference)
//
#include <hip/hip_runtime.h>

// Problem dims
constexpr int VOC  = 50005;
constexpr int BB   = 32;
constexpr int TT   = 64;
constexpr int NR   = 2048;   // B*T
constexpr int EM   = 512;    // EMB
constexpr int HD   = 1024;   // HID
constexpr int SS   = 1024;   // SES
constexpr int E2   = 1024;   // 2*EMB
constexpr int G3   = 3072;   // 3*HID
constexpr int KSN  = 8784;   // KNOW-1
constexpr int KS_LO = 10;
constexpr int KS_HI = 10 + KSN; // 8794
constexpr float NPAD = 41221.0f; // 10 + (VOC - 10 - KSN)
constexpr int NVB  = 782;    // ceil(VOC/64) vocab tiles of k_big

__device__ __forceinline__ float dot4(float4 a, float4 b) {
    return a.x*b.x + a.y*b.y + a.z*b.z + a.w*b.w;
}
__device__ __forceinline__ float sigmoidf_(float x) { return 1.0f / (1.0f + expf(-x)); }

// ---------------------------------------------------------------- K1: gather
__global__ __launch_bounds__(128) void k_gather(const float* __restrict__ embed,
                                                const int* __restrict__ target,
                                                float* __restrict__ TE) {
    int n = blockIdx.x;                 // 2048
    int row = target[n];
    const float4* s = (const float4*)(embed + (size_t)row * EM);
    float4* d = (float4*)(TE + (size_t)n * EM);
    d[threadIdx.x] = s[threadIdx.x];    // 128 float4 = 512 floats
}

// ------------------------------------------------- K2: h0 + ses_inf_vec
__global__ __launch_bounds__(256) void k_h0_sesinf(const float* __restrict__ ses,
                                                   const float* __restrict__ sdw,
                                                   const float* __restrict__ sdb,
                                                   const float* __restrict__ siw,
                                                   float* __restrict__ h0,
                                                   float* __restrict__ sesinf) {
    int g = blockIdx.x * 256 + threadIdx.x;  // 8192 total
    int b = g & 31;
    int jg = g >> 5;                          // 0..255
    int j0 = jg * 4;
    const float4* s4 = (const float4*)(ses + (size_t)b * SS);
    const float4* wa[4];
    const float4* wc[4];
#pragma unroll
    for (int r = 0; r < 4; ++r) {
        wa[r] = (const float4*)(sdw + (size_t)(j0 + r) * SS);
        wc[r] = (const float4*)(siw + (size_t)(j0 + r) * SS);
    }
    float a[4] = {0, 0, 0, 0}, c[4] = {0, 0, 0, 0};
    for (int kq = 0; kq < SS / 4; ++kq) {
        float4 sv = s4[kq];
#pragma unroll
        for (int r = 0; r < 4; ++r) {
            a[r] += dot4(sv, wa[r][kq]);
            c[r] += dot4(sv, wc[r][kq]);
        }
    }
#pragma unroll
    for (int r = 0; r < 4; ++r) {
        h0[b * HD + j0 + r] = tanhf(a[r] + sdb[j0 + r]);
        sesinf[b * E2 + j0 + r] = c[r];
    }
}

// ------------------------------------------------- K3: gate_const = ses@W1.T + know@W2.T
__global__ __launch_bounds__(256) void k_gateconst(const float* __restrict__ ses,
                                                   const float* __restrict__ know,
                                                   const float* __restrict__ W1,
                                                   const float* __restrict__ W2,
                                                   float* __restrict__ gc) {
    int g = blockIdx.x * 256 + threadIdx.x;
    int b = g & 31;
    int vg = g >> 5;
    if (vg >= 6251) return;                  // ceil(VOC/8)
    int v0 = vg * 8;
    const float4* s4 = (const float4*)(ses + (size_t)b * SS);
    const float4* k4 = (const float4*)(know + (size_t)b * SS);
    const float4* w1p[8];
    const float4* w2p[8];
#pragma unroll
    for (int r = 0; r < 8; ++r) {
        int v = min(v0 + r, VOC - 1);
        w1p[r] = (const float4*)(W1 + (size_t)v * SS);
        w2p[r] = (const float4*)(W2 + (size_t)v * SS);
    }
    float acc[8] = {0, 0, 0, 0, 0, 0, 0, 0};
    for (int kq = 0; kq < SS / 4; ++kq) {
        float4 sv = s4[kq];
        float4 kv = k4[kq];
#pragma unroll
        for (int r = 0; r < 8; ++r)
            acc[r] += dot4(sv, w1p[r][kq]) + dot4(kv, w2p[r][kq]);
    }
#pragma unroll
    for (int r = 0; r < 8; ++r)
        if (v0 + r < VOC) gc[(size_t)b * VOC + v0 + r] = acc[r];
}

// ------------------------------------------------- K4a: ks = know @ know_vote_w.T (cols 0..8783)
__global__ __launch_bounds__(256) void k_ks(const float* __restrict__ know,
                                            const float* __restrict__ kvw,
                                            float* __restrict__ ks) {
    int g = blockIdx.x * 256 + threadIdx.x;
    if (g >= 32 * 2196) return;              // 8784/4 = 2196 groups
    int b = g & 31;
    int jg = g >> 5;
    int j0 = jg * 4;
    const float4* k4 = (const float4*)(know + (size_t)b * SS);
    const float4* wp[4];
#pragma unroll
    for (int r = 0; r < 4; ++r) wp[r] = (const float4*)(kvw + (size_t)(j0 + r) * SS);
    float acc[4] = {0, 0, 0, 0};
    for (int kq = 0; kq < SS / 4; ++kq) {
        float4 kv = k4[kq];
#pragma unroll
        for (int r = 0; r < 4; ++r) acc[r] += dot4(kv, wp[r][kq]);
    }
#pragma unroll
    for (int r = 0; r < 4; ++r) ks[(size_t)b * KSN + j0 + r] = acc[r];
}

// ------------------------------------------------- K4b: lse of padded know scores
__global__ __launch_bounds__(256) void k_lseknow(const float* __restrict__ ks,
                                                 float* __restrict__ lsek) {
    int b = blockIdx.x;
    int t = threadIdx.x;
    __shared__ float sm[256];
    float m = -1e30f;
    for (int j = t; j < KSN; j += 256) m = fmaxf(m, ks[(size_t)b * KSN + j]);
    sm[t] = m;
    __syncthreads();
    for (int s = 128; s > 0; s >>= 1) {
        if (t < s) sm[t] = fmaxf(sm[t], sm[t + s]);
        __syncthreads();
    }
    m = fmaxf(sm[0], 0.0f);                  // pads (= exp(-100) ~ 0) included in max
    __syncthreads();
    float s = 0.0f;
    for (int j = t; j < KSN; j += 256) s += expf(ks[(size_t)b * KSN + j] - m);
    sm[t] = s;
    __syncthreads();
    for (int r = 128; r > 0; r >>= 1) {
        if (t < r) sm[t] += sm[t + r];
        __syncthreads();
    }
    if (t == 0) lsek[b] = m + logf(sm[0] + NPAD * expf(0.0f - m));
}

// ------------------------------------------------- K5: GI = TE @ W_ih.T + b_ih
__global__ __launch_bounds__(256) void k_gi(const float* __restrict__ TE,
                                            const float* __restrict__ Wih,
                                            const float* __restrict__ bih,
                                            float* __restrict__ GI) {
    int g = blockIdx.x * 256 + threadIdx.x;  // 786432 = 384*2048
    int n = g & 2047;
    int jg = g >> 11;                        // 0..383
    int j0 = jg * 8;
    const float4* t4 = (const float4*)(TE + (size_t)n * EM);
    const float4* wp[8];
#pragma unroll
    for (int r = 0; r < 8; ++r) wp[r] = (const float4*)(Wih + (size_t)(j0 + r) * EM);
    float acc[8] = {0, 0, 0, 0, 0, 0, 0, 0};
    for (int kq = 0; kq < EM / 4; ++kq) {
        float4 x = t4[kq];
#pragma unroll
        for (int r = 0; r < 8; ++r) acc[r] += dot4(x, wp[r][kq]);
    }
#pragma unroll
    for (int r = 0; r < 8; ++r) GI[(size_t)n * G3 + j0 + r] = acc[r] + bih[j0 + r];
}

// ------------------------------------------------- K6: one GRU step (torch variant)
__global__ __launch_bounds__(256) void k_gru(const float* __restrict__ GI,
                                             const float* __restrict__ Whh,
                                             const float* __restrict__ bhh,
                                             const float* __restrict__ h0,
                                             float* __restrict__ Hall, int t) {
    int g = blockIdx.x * 256 + threadIdx.x;  // 32768
    int b = g & 31;
    int j = g >> 5;                          // 0..1023
    const float* hp = (t == 0) ? (h0 + (size_t)b * HD)
                               : (Hall + ((size_t)b * TT + (t - 1)) * HD);
    const float4* h4 = (const float4*)hp;
    const float4* wr = (const float4*)(Whh + (size_t)j * HD);
    const float4* wz = (const float4*)(Whh + (size_t)(j + HD) * HD);
    const float4* wn = (const float4*)(Whh + (size_t)(j + 2 * HD) * HD);
    float ar = 0, az = 0, an = 0;
    for (int kq = 0; kq < HD / 4; ++kq) {
        float4 h = h4[kq];
        ar += dot4(h, wr[kq]);
        az += dot4(h, wz[kq]);
        an += dot4(h, wn[kq]);
    }
    int n = b * TT + t;
    float ir  = GI[(size_t)n * G3 + j];
    float iz  = GI[(size_t)n * G3 + HD + j];
    float inn = GI[(size_t)n * G3 + 2 * HD + j];
    float r = sigmoidf_(ir + ar + bhh[j]);
    float z = sigmoidf_(iz + az + bhh[HD + j]);
    float nn = tanhf(inn + r * (an + bhh[2 * HD + j]));
    Hall[(size_t)n * HD + j] = (1.0f - z) * nn + z * hp[j];
}

// ------------------------------------------------- K7: maxout input MX
__global__ __launch_bounds__(256) void k_mx(const float* __restrict__ Hall,
                                            const float* __restrict__ TE,
                                            const float* __restrict__ dw,
                                            const float* __restrict__ ew,
                                            const float* __restrict__ eb,
                                            const float* __restrict__ sesinf,
                                            float* __restrict__ MX) {
    int g = blockIdx.x * 256 + threadIdx.x;  // 262144 = 128*2048
    int n = g & 2047;
    int eg = g >> 11;                        // 0..127
    int j0 = eg * 8;
    int b = n >> 6;
    const float4* h4 = (const float4*)(Hall + (size_t)n * HD);
    const float4* t4 = (const float4*)(TE + (size_t)n * EM);
    float acc[8] = {0, 0, 0, 0, 0, 0, 0, 0};
    {
        const float4* wp[8];
#pragma unroll
        for (int r = 0; r < 8; ++r) wp[r] = (const float4*)(dw + (size_t)(j0 + r) * HD);
        for (int kq = 0; kq < HD / 4; ++kq) {
            float4 h = h4[kq];
#pragma unroll
            for (int r = 0; r < 8; ++r) acc[r] += dot4(h, wp[r][kq]);
        }
    }
    {
        const float4* wp[8];
#pragma unroll
        for (int r = 0; r < 8; ++r) wp[r] = (const float4*)(ew + (size_t)(j0 + r) * EM);
        for (int kq = 0; kq < EM / 4; ++kq) {
            float4 x = t4[kq];
#pragma unroll
            for (int r = 0; r < 8; ++r) acc[r] += dot4(x, wp[r][kq]);
        }
    }
#pragma unroll
    for (int r = 0; r < 8; ++r) acc[r] += sesinf[(size_t)b * E2 + j0 + r] + eb[j0 + r];
#pragma unroll
    for (int p = 0; p < 4; ++p)
        MX[(size_t)n * EM + eg * 4 + p] = fmaxf(acc[2 * p], acc[2 * p + 1]);
}

// ------------------------------------------------- K8: fused vocab GEMM + gate + partial softmax
// BM=64 (vocab) x BN=128 (rows), KC=64, thread tile 4v x 8n, 256 threads.
__global__ __launch_bounds__(256) void k_big(const float* __restrict__ embed,
                                             const float* __restrict__ W3,
                                             const float* __restrict__ W4,
                                             const float* __restrict__ MX,
                                             const float* __restrict__ Hall,
                                             const float* __restrict__ TE,
                                             const float* __restrict__ gc,
                                             const float* __restrict__ ks,
                                             const float* __restrict__ lsek,
                                             float* __restrict__ out,
                                             unsigned char* __restrict__ g8,
                                             float* __restrict__ pmax,
                                             float* __restrict__ psum) {
    __shared__ float A_l[64][68];    // k-major, 64 vocab rows
    __shared__ float B_l[64][132];   // k-major, 128 batch rows
    __shared__ float red[128][17];
    __shared__ float rowm[128];
    int tid = threadIdx.x;
    int tv = tid & 15;               // vocab frag: rows tv*4..tv*4+3
    int tn = tid >> 4;               // row frag:  cols tn*8..tn*8+7
    int vb = blockIdx.x * 64;

#define STAGE(ASRC, ALEN, BSRC, BLEN, KO)                                             \
    {                                                                                 \
        _Pragma("unroll") for (int p = 0; p < 4; ++p) {                               \
            int f = tid + p * 256;                                                    \
            int row = f >> 4;                                                         \
            int kk = (f & 15) * 4;                                                    \
            int v = vb + row;                                                         \
            float4 av = (v < VOC)                                                     \
                            ? *(const float4*)(ASRC + (size_t)v * ALEN + (KO) + kk)   \
                            : make_float4(0.f, 0.f, 0.f, 0.f);                        \
            A_l[kk + 0][row] = av.x; A_l[kk + 1][row] = av.y;                         \
            A_l[kk + 2][row] = av.z; A_l[kk + 3][row] = av.w;                         \
        }                                                                             \
        _Pragma("unroll") for (int p = 0; p < 8; ++p) {                               \
            int f = tid + p * 256;                                                    \
            int row = f >> 4;                                                         \
            int kk = (f & 15) * 4;                                                    \
            int n = nb + row;                                                         \
            float4 bv = *(const float4*)(BSRC + (size_t)n * BLEN + (KO) + kk);        \
            B_l[kk + 0][row] = bv.x; B_l[kk + 1][row] = bv.y;                         \
            B_l[kk + 2][row] = bv.z; B_l[kk + 3][row] = bv.w;                         \
        }                                                                             \
    }

#define COMPUTE(ACC)                                                                  \
    {                                                                                 \
        _Pragma("unroll 8") for (int k = 0; k < 64; ++k) {                            \
            float4 a  = *(const float4*)&A_l[k][tv * 4];                              \
            float4 b0 = *(const float4*)&B_l[k][tn * 8];                              \
            float4 b1 = *(const float4*)&B_l[k][tn * 8 + 4];                          \
            float aa[4] = {a.x, a.y, a.z, a.w};                                       \
            float bb[8] = {b0.x, b0.y, b0.z, b0.w, b1.x, b1.y, b1.z, b1.w};           \
            _Pragma("unroll") for (int i = 0; i < 4; ++i)                             \
                _Pragma("unroll") for (int j2 = 0; j2 < 8; ++j2)                      \
                    ACC[i][j2] += aa[i] * bb[j2];                                     \
        }                                                                             \
    }

    for (int nt = 0; nt < 16; ++nt) {
        int nb = nt * 128;
        float accL[4][8];
        float accG[4][8];
#pragma unroll
        for (int i = 0; i < 4; ++i)
#pragma unroll
            for (int j2 = 0; j2 < 8; ++j2) { accL[i][j2] = 0.f; accG[i][j2] = 0.f; }

        for (int kt = 0; kt < 512; kt += 64) {          // logits: embed . MX
            STAGE(embed, EM, MX, EM, kt);
            __syncthreads();
            COMPUTE(accL);
            __syncthreads();
        }
        for (int kt = 0; kt < 1024; kt += 64) {         // l3: W3 . Hall
            STAGE(W3, HD, Hall, HD, kt);
            __syncthreads();
            COMPUTE(accG);
            __syncthreads();
        }
        for (int kt = 0; kt < 512; kt += 64) {          // l4: W4 . TE
            STAGE(W4, EM, TE, EM, kt);
            __syncthreads();
            COMPUTE(accG);
            __syncthreads();
        }

        // ---- epilogue: write P + quantized gate, partial row max/sumexp ----
#pragma unroll
        for (int jj = 0; jj < 8; ++jj) {
            float lm = -1e30f;
#pragma unroll
            for (int i = 0; i < 4; ++i) {
                int v = vb + tv * 4 + i;
                if (v < VOC) lm = fmaxf(lm, accL[i][jj]);
            }
            red[tn * 8 + jj][tv] = lm;
        }
        __syncthreads();
        if (tid < 128) {
            float m = red[tid][0];
#pragma unroll
            for (int q = 1; q < 16; ++q) m = fmaxf(m, red[tid][q]);
            rowm[tid] = m;
        }
        __syncthreads();
#pragma unroll
        for (int jj = 0; jj < 8; ++jj) {
            int n = nb + tn * 8 + jj;
            int b = n >> 6;
            float m = rowm[tn * 8 + jj];
            float lsekb = lsek[b];
            float s = 0.0f;
#pragma unroll
            for (int i = 0; i < 4; ++i) {
                int v = vb + tv * 4 + i;
                if (v >= VOC) continue;
                float logit = accL[i][jj];
                s += expf(logit - m);
                float garg = gc[(size_t)b * VOC + v] + accG[i][jj];
                float gate = 1.0f / (1.0f + expf(-garg));
                float kp = ((v >= KS_LO && v < KS_HI) ? ks[(size_t)b * KSN + (v - KS_LO)] : 0.0f) - lsekb;
                size_t idx = (size_t)n * VOC + v;
                out[idx] = gate * logit + (1.0f - gate) * kp;
                g8[idx] = (unsigned char)(gate * 255.0f + 0.5f);
            }
            red[tn * 8 + jj][tv] = s;
        }
        __syncthreads();
        if (tid < 128) {
            float s = 0.f;
#pragma unroll
            for (int q = 0; q < 16; ++q) s += red[tid][q];
            int n = nb + tid;
            pmax[(size_t)n * NVB + blockIdx.x] = rowm[tid];
            psum[(size_t)n * NVB + blockIdx.x] = s;
        }
        __syncthreads();
    }
#undef STAGE
#undef COMPUTE
}

// ------------------------------------------------- K9: per-row lse from partials
__global__ __launch_bounds__(256) void k_lse(const float* __restrict__ pmax,
                                             const float* __restrict__ psum,
                                             float* __restrict__ lse) {
    int n = blockIdx.x;
    int t = threadIdx.x;
    __shared__ float sm[256];
    const float* pm = pmax + (size_t)n * NVB;
    const float* ps = psum + (size_t)n * NVB;
    float m = -1e30f;
    for (int p = t; p < NVB; p += 256) m = fmaxf(m, pm[p]);
    sm[t] = m;
    __syncthreads();
    for (int s = 128; s > 0; s >>= 1) {
        if (t < s) sm[t] = fmaxf(sm[t], sm[t + s]);
        __syncthreads();
    }
    m = sm[0];
    __syncthreads();
    float s = 0.0f;
    for (int p = t; p < NVB; p += 256) s += ps[p] * expf(pm[p] - m);
    sm[t] = s;
    __syncthreads();
    for (int r = 128; r > 0; r >>= 1) {
        if (t < r) sm[t] += sm[t + r];
        __syncthreads();
    }
    if (t == 0) lse[n] = m + logf(sm[0]);
}

// ------------------------------------------------- K10: out = P - gate*lse
__global__ __launch_bounds__(256) void k_final(float* __restrict__ out,
                                               const unsigned char* __restrict__ g8,
                                               const float* __restrict__ lse) {
    int n = blockIdx.y;
    int v0 = blockIdx.x * 4096;
    float l = lse[n];
    size_t base = (size_t)n * VOC;
#pragma unroll
    for (int u = 0; u < 16; ++u) {
        int v = v0 + u * 256 + threadIdx.x;
        if (v < VOC) {
            size_t idx = base + v;
            float gq = g8[idx] * (1.0f / 255.0f);
            out[idx] = out[idx] - gq * l;
        }
    }
}

// ---------------------------------------------------------------- launch
extern "C" void kernel_launch(void* const* d_in, const int* in_sizes, int n_in,
                              void* d_out, int out_size, void* d_ws, size_t ws_size,
                              hipStream_t stream) {
    const float* ses    = (const float*)d_in[0];
    const float* know   = (const float*)d_in[1];
    const int*   target = (const int*)d_in[2];
    const float* embed  = (const float*)d_in[3];
    const float* Wih    = (const float*)d_in[4];
    const float* Whh    = (const float*)d_in[5];
    const float* bih    = (const float*)d_in[6];
    const float* bhh    = (const float*)d_in[7];
    const float* sdw    = (const float*)d_in[8];
    const float* sdb    = (const float*)d_in[9];
    const float* dw     = (const float*)d_in[10];
    const float* siw    = (const float*)d_in[11];
    const float* ew     = (const float*)d_in[12];
    const float* eb     = (const float*)d_in[13];
    const float* W1     = (const float*)d_in[14];
    const float* W2     = (const float*)d_in[15];
    const float* W3     = (const float*)d_in[16];
    const float* W4     = (const float*)d_in[17];
    const float* kvw    = (const float*)d_in[18];

    // ws layout (float offsets); total ~157 MB
    float* ws     = (float*)d_ws;
    float* TE     = ws + 0;          //  2048*512
    float* MX     = ws + 1048576;    //  2048*512
    float* Hall   = ws + 2097152;    //  2048*1024
    float* GI     = ws + 4194304;    //  2048*3072
    float* h0     = ws + 10485760;   //  32*1024
    float* sesinf = ws + 10518528;   //  32*1024
    float* gc     = ws + 10551296;   //  32*50005
    float* ksb    = ws + 12151456;   //  32*8784
    float* lsek   = ws + 12432544;   //  32
    float* lse    = ws + 12432576;   //  2048
    float* pmax   = ws + 12434624;   //  2048*782
    float* psum   = ws + 14036160;   //  2048*782
    unsigned char* g8 = (unsigned char*)(ws + 15637696); // 2048*50005 bytes
    float* out = (float*)d_out;

    k_gather<<<dim3(2048), dim3(128), 0, stream>>>(embed, target, TE);
    k_h0_sesinf<<<dim3(32), dim3(256), 0, stream>>>(ses, sdw, sdb, siw, h0, sesinf);
    k_gateconst<<<dim3(782), dim3(256), 0, stream>>>(ses, know, W1, W2, gc);
    k_ks<<<dim3(275), dim3(256), 0, stream>>>(know, kvw, ksb);
    k_lseknow<<<dim3(32), dim3(256), 0, stream>>>(ksb, lsek);
    k_gi<<<dim3(3072), dim3(256), 0, stream>>>(TE, Wih, bih, GI);
    for (int t = 0; t < TT; ++t)
        k_gru<<<dim3(128), dim3(256), 0, stream>>>(GI, Whh, bhh, h0, Hall, t);
    k_mx<<<dim3(1024), dim3(256), 0, stream>>>(Hall, TE, dw, ew, eb, sesinf, MX);
    k_big<<<dim3(NVB), dim3(256), 0, stream>>>(embed, W3, W4, MX, Hall, TE, gc, ksb,
                                               lsek, out, g8, pmax, psum);
    k_lse<<<dim3(2048), dim3(256), 0, stream>>>(pmax, psum, lse);
    k_final<<<dim3(13, 2048), dim3(256), 0, stream>>>(out, g8, lse);
}

// Round 2
// 3664.016 us; speedup vs baseline: 4.7085x; 4.7085x over previous
//
#include <hip/hip_runtime.h>

// Problem dims
constexpr int VOC  = 50005;
constexpr int VOCP = 50048;   // 391*128, padded vocab
constexpr int NTM  = 391;     // vocab tiles (128) for big GEMMs
constexpr int NTMP = 400;     // padded partial stride
constexpr int KSN  = 8784;    // KNOW-1
constexpr float NPAD = 41221.0f;

typedef unsigned short u16;
typedef __attribute__((ext_vector_type(4))) float f32x4;
typedef __attribute__((ext_vector_type(8))) short bf16x8;

__device__ __forceinline__ float dot4(float4 a, float4 b) {
    return a.x*b.x + a.y*b.y + a.z*b.z + a.w*b.w;
}
__device__ __forceinline__ float sigmoidf_(float x) { return 1.0f / (1.0f + expf(-x)); }
__device__ __forceinline__ u16 f2bf(float f) {
    unsigned x = __float_as_uint(f);
    return (u16)((x + 0x7FFFu + ((x >> 16) & 1u)) >> 16);
}
__device__ __forceinline__ float bf2f(u16 u) { return __uint_as_float(((unsigned)u) << 16); }
__device__ __forceinline__ void gload_lds16(const void* g, void* l) {
    __builtin_amdgcn_global_load_lds((const __attribute__((address_space(1))) unsigned int*)g,
                                     (__attribute__((address_space(3))) unsigned int*)l, 16, 0, 0);
}

// ---------------------------------------------------------------- cvt fp32 -> bf16 (strided)
__global__ __launch_bounds__(256) void k_cvt(const float* __restrict__ src, u16* __restrict__ dst,
                                             int ncols, int sld, int dld) {
    int row = blockIdx.x;
    int c = (blockIdx.y * 256 + threadIdx.x) * 4;
    if (c >= ncols) return;
    float4 v = *(const float4*)(src + (size_t)row * sld + c);
    unsigned lo = f2bf(v.x) | ((unsigned)f2bf(v.y) << 16);
    unsigned hi = f2bf(v.z) | ((unsigned)f2bf(v.w) << 16);
    *(uint2*)(dst + (size_t)row * dld + c) = make_uint2(lo, hi);
}

// zero pad rows 50005..50047 of Aemb / A34
__global__ __launch_bounds__(256) void k_pad0(u16* __restrict__ Aemb, u16* __restrict__ A34) {
    int r = VOC + blockIdx.x;
    unsigned* pe = (unsigned*)(Aemb + (size_t)r * 512);
    if (threadIdx.x < 256) pe[threadIdx.x] = 0;
    unsigned* p3 = (unsigned*)(A34 + (size_t)r * 1536);
    for (int i = threadIdx.x; i < 768; i += 256) p3[i] = 0;
}

// ---------------------------------------------------------------- gather target embeddings -> BG[:,1024:1536] bf16
__global__ __launch_bounds__(128) void k_gather(const float* __restrict__ embed,
                                                const int* __restrict__ target,
                                                u16* __restrict__ BG) {
    int n = blockIdx.x;
    int row = target[n];
    int c = threadIdx.x * 4;
    float4 v = *(const float4*)(embed + (size_t)row * 512 + c);
    unsigned lo = f2bf(v.x) | ((unsigned)f2bf(v.y) << 16);
    unsigned hi = f2bf(v.z) | ((unsigned)f2bf(v.w) << 16);
    *(uint2*)(BG + (size_t)n * 1536 + 1024 + c) = make_uint2(lo, hi);
}

// ------------------------------------------------- h0 + ses_inf_vec (fp32, small)
__global__ __launch_bounds__(256) void k_h0_sesinf(const float* __restrict__ ses,
                                                   const float* __restrict__ sdw,
                                                   const float* __restrict__ sdb,
                                                   const float* __restrict__ siw,
                                                   float* __restrict__ h0,
                                                   float* __restrict__ sesinf) {
    int g = blockIdx.x * 256 + threadIdx.x;
    int b = g & 31;
    int jg = g >> 5;
    int j0 = jg * 4;
    const float4* s4 = (const float4*)(ses + (size_t)b * 1024);
    const float4* wa[4];
    const float4* wc[4];
#pragma unroll
    for (int r = 0; r < 4; ++r) {
        wa[r] = (const float4*)(sdw + (size_t)(j0 + r) * 1024);
        wc[r] = (const float4*)(siw + (size_t)(j0 + r) * 1024);
    }
    float a[4] = {0, 0, 0, 0}, c[4] = {0, 0, 0, 0};
    for (int kq = 0; kq < 256; ++kq) {
        float4 sv = s4[kq];
#pragma unroll
        for (int r = 0; r < 4; ++r) { a[r] += dot4(sv, wa[r][kq]); c[r] += dot4(sv, wc[r][kq]); }
    }
#pragma unroll
    for (int r = 0; r < 4; ++r) {
        h0[b * 1024 + j0 + r] = tanhf(a[r] + sdb[j0 + r]);
        sesinf[b * 1024 + j0 + r] = c[r];
    }
}

// ------------------------------------------------- gate_const = ses@W1.T + know@W2.T (VOCP stride)
__global__ __launch_bounds__(256) void k_gateconst(const float* __restrict__ ses,
                                                   const float* __restrict__ know,
                                                   const float* __restrict__ W1,
                                                   const float* __restrict__ W2,
                                                   float* __restrict__ gc) {
    int g = blockIdx.x * 256 + threadIdx.x;
    int b = g & 31;
    int vg = g >> 5;
    if (vg >= 6251) return;
    int v0 = vg * 8;
    const float4* s4 = (const float4*)(ses + (size_t)b * 1024);
    const float4* k4 = (const float4*)(know + (size_t)b * 1024);
    const float4* w1p[8];
    const float4* w2p[8];
#pragma unroll
    for (int r = 0; r < 8; ++r) {
        int v = min(v0 + r, VOC - 1);
        w1p[r] = (const float4*)(W1 + (size_t)v * 1024);
        w2p[r] = (const float4*)(W2 + (size_t)v * 1024);
    }
    float acc[8] = {0, 0, 0, 0, 0, 0, 0, 0};
    for (int kq = 0; kq < 256; ++kq) {
        float4 sv = s4[kq];
        float4 kv = k4[kq];
#pragma unroll
        for (int r = 0; r < 8; ++r) acc[r] += dot4(sv, w1p[r][kq]) + dot4(kv, w2p[r][kq]);
    }
#pragma unroll
    for (int r = 0; r < 8; ++r)
        if (v0 + r < VOC) gc[(size_t)b * VOCP + v0 + r] = acc[r];
}

// ------------------------------------------------- ks = know @ know_vote_w.T
__global__ __launch_bounds__(256) void k_ks(const float* __restrict__ know,
                                            const float* __restrict__ kvw,
                                            float* __restrict__ ks) {
    int g = blockIdx.x * 256 + threadIdx.x;
    if (g >= 32 * 2196) return;
    int b = g & 31;
    int j0 = (g >> 5) * 4;
    const float4* k4 = (const float4*)(know + (size_t)b * 1024);
    const float4* wp[4];
#pragma unroll
    for (int r = 0; r < 4; ++r) wp[r] = (const float4*)(kvw + (size_t)(j0 + r) * 1024);
    float acc[4] = {0, 0, 0, 0};
    for (int kq = 0; kq < 256; ++kq) {
        float4 kv = k4[kq];
#pragma unroll
        for (int r = 0; r < 4; ++r) acc[r] += dot4(kv, wp[r][kq]);
    }
#pragma unroll
    for (int r = 0; r < 4; ++r) ks[(size_t)b * KSN + j0 + r] = acc[r];
}

// ------------------------------------------------- lse of padded know scores
__global__ __launch_bounds__(256) void k_lseknow(const float* __restrict__ ks,
                                                 float* __restrict__ lsek) {
    int b = blockIdx.x;
    int t = threadIdx.x;
    __shared__ float sm[256];
    float m = -1e30f;
    for (int j = t; j < KSN; j += 256) m = fmaxf(m, ks[(size_t)b * KSN + j]);
    sm[t] = m;
    __syncthreads();
    for (int s = 128; s > 0; s >>= 1) { if (t < s) sm[t] = fmaxf(sm[t], sm[t + s]); __syncthreads(); }
    m = fmaxf(sm[0], 0.0f);
    __syncthreads();
    float s = 0.0f;
    for (int j = t; j < KSN; j += 256) s += expf(ks[(size_t)b * KSN + j] - m);
    sm[t] = s;
    __syncthreads();
    for (int r = 128; r > 0; r >>= 1) { if (t < r) sm[t] += sm[t + r]; __syncthreads(); }
    if (t == 0) lsek[b] = m + logf(sm[0] + NPAD * expf(0.0f - m));
}

// ================================================= templated bf16 MFMA GEMM (C[m][n] = A[m]·B[n])
// EPI 0: GI (+bias, fp32 store)   EPI 1: MX maxout (+sesinf+eb, bf16 store)
// EPI 2: gate (gc+sigmoid, u8)    EPI 3: logits (bf16 store + softmax partials)
template<int EPI>
__global__ __launch_bounds__(256) void gemm_bt(
    const u16* __restrict__ A, int lda,
    const u16* __restrict__ B, int ldb, int K,
    const float* __restrict__ p0, const float* __restrict__ p1,
    float* __restrict__ q0, u16* __restrict__ q1,
    unsigned char* __restrict__ q2, float* __restrict__ q3)
{
    __shared__ u16 Asm[128 * 64];
    __shared__ u16 Bsm[128 * 64];
    const int tid = threadIdx.x;
    const int lane = tid & 63;
    const int w = tid >> 6;
    const int wm = w >> 1, wn = w & 1;
    const int nt = blockIdx.x, mt = blockIdx.y;

    f32x4 acc[4][4];
#pragma unroll
    for (int i = 0; i < 4; ++i)
#pragma unroll
        for (int j = 0; j < 4; ++j) acc[i][j] = (f32x4){0.f, 0.f, 0.f, 0.f};

    for (int kt = 0; kt < K; kt += 64) {
#pragma unroll
        for (int p = 0; p < 4; ++p) {
            int flat = (w * 4 + p) * 64 + lane;       // 0..1023 16B-slots
            int row = flat >> 3, slot = flat & 7;
            int ss = slot ^ (row & 7);                // inverse-swizzled source slot
            gload_lds16(A + (size_t)(mt * 128 + row) * lda + kt + ss * 8, Asm + flat * 8);
            gload_lds16(B + (size_t)(nt * 128 + row) * ldb + kt + ss * 8, Bsm + flat * 8);
        }
        __syncthreads();
#pragma unroll
        for (int kc = 0; kc < 2; ++kc) {
            bf16x8 af[4], bfr[4];
#pragma unroll
            for (int mi = 0; mi < 4; ++mi) {
                int row = wm * 64 + mi * 16 + (lane & 15);
                int bcol = kc * 64 + ((lane >> 4) << 4);
                af[mi] = *(const bf16x8*)((const char*)Asm + row * 128 + (bcol ^ ((row & 7) << 4)));
            }
#pragma unroll
            for (int ni = 0; ni < 4; ++ni) {
                int row = wn * 64 + ni * 16 + (lane & 15);
                int bcol = kc * 64 + ((lane >> 4) << 4);
                bfr[ni] = *(const bf16x8*)((const char*)Bsm + row * 128 + (bcol ^ ((row & 7) << 4)));
            }
#pragma unroll
            for (int mi = 0; mi < 4; ++mi)
#pragma unroll
                for (int ni = 0; ni < 4; ++ni)
                    acc[mi][ni] = __builtin_amdgcn_mfma_f32_16x16x32_bf16(af[mi], bfr[ni], acc[mi][ni], 0, 0, 0);
        }
        __syncthreads();
    }

    const int cl = lane & 15;           // n offset within fragment
    const int rg = (lane >> 4) << 2;    // m base within fragment

    if constexpr (EPI == 0) {           // GI = TE@Wih.T + bih  (fp32 [n][3072])
#pragma unroll
        for (int mi = 0; mi < 4; ++mi) {
            int m0 = mt * 128 + wm * 64 + mi * 16 + rg;
            float4 bias = *(const float4*)(p0 + m0);
#pragma unroll
            for (int ni = 0; ni < 4; ++ni) {
                int n = nt * 128 + wn * 64 + ni * 16 + cl;
                float4 v;
                v.x = acc[mi][ni][0] + bias.x; v.y = acc[mi][ni][1] + bias.y;
                v.z = acc[mi][ni][2] + bias.z; v.w = acc[mi][ni][3] + bias.w;
                *(float4*)(q0 + (size_t)n * 3072 + m0) = v;
            }
        }
    }
    if constexpr (EPI == 1) {           // maxout -> BL bf16 [n][512]
#pragma unroll
        for (int mi = 0; mi < 4; ++mi) {
            int m0 = mt * 128 + wm * 64 + mi * 16 + rg;
            float4 eb4 = *(const float4*)(p1 + m0);
#pragma unroll
            for (int ni = 0; ni < 4; ++ni) {
                int n = nt * 128 + wn * 64 + ni * 16 + cl;
                int b = n >> 6;
                float v0 = acc[mi][ni][0] + p0[b * 1024 + m0 + 0] + eb4.x;
                float v1 = acc[mi][ni][1] + p0[b * 1024 + m0 + 1] + eb4.y;
                float v2 = acc[mi][ni][2] + p0[b * 1024 + m0 + 2] + eb4.z;
                float v3 = acc[mi][ni][3] + p0[b * 1024 + m0 + 3] + eb4.w;
                unsigned pk = f2bf(fmaxf(v0, v1)) | ((unsigned)f2bf(fmaxf(v2, v3)) << 16);
                *(unsigned*)(q1 + (size_t)n * 512 + (m0 >> 1)) = pk;
            }
        }
    }
    if constexpr (EPI == 2) {           // gate -> g8 u8 [n][VOCP]
#pragma unroll
        for (int mi = 0; mi < 4; ++mi) {
            int v0 = mt * 128 + wm * 64 + mi * 16 + rg;
#pragma unroll
            for (int ni = 0; ni < 4; ++ni) {
                int n = nt * 128 + wn * 64 + ni * 16 + cl;
                int b = n >> 6;
                float4 gcv = *(const float4*)(p0 + (size_t)b * VOCP + v0);
                unsigned pk = 0;
#pragma unroll
                for (int r = 0; r < 4; ++r) {
                    float garg = acc[mi][ni][r] + ((const float*)&gcv)[r];
                    float gate = 1.0f / (1.0f + expf(-garg));
                    pk |= ((unsigned)(int)(gate * 255.0f + 0.5f)) << (8 * r);
                }
                *(unsigned*)(q2 + (size_t)n * VOCP + v0) = pk;
            }
        }
    }
    if constexpr (EPI == 3) {           // logits -> Lb bf16 [n][VOCP] + partial max/sumexp
        __shared__ float redm[2][128];
        __shared__ float reds[2][128];
#pragma unroll
        for (int mi = 0; mi < 4; ++mi) {
            int v0 = mt * 128 + wm * 64 + mi * 16 + rg;
#pragma unroll
            for (int ni = 0; ni < 4; ++ni) {
                int n = nt * 128 + wn * 64 + ni * 16 + cl;
                unsigned lo = f2bf(acc[mi][ni][0]) | ((unsigned)f2bf(acc[mi][ni][1]) << 16);
                unsigned hi = f2bf(acc[mi][ni][2]) | ((unsigned)f2bf(acc[mi][ni][3]) << 16);
                *(uint2*)(q1 + (size_t)n * VOCP + v0) = make_uint2(lo, hi);
            }
        }
#pragma unroll
        for (int ni = 0; ni < 4; ++ni) {
            float lm = -1e30f;
#pragma unroll
            for (int mi = 0; mi < 4; ++mi) {
                int v0 = mt * 128 + wm * 64 + mi * 16 + rg;
#pragma unroll
                for (int r = 0; r < 4; ++r)
                    if (v0 + r < VOC) lm = fmaxf(lm, acc[mi][ni][r]);
            }
            lm = fmaxf(lm, __shfl_xor(lm, 16));
            lm = fmaxf(lm, __shfl_xor(lm, 32));
            float s = 0.0f;
#pragma unroll
            for (int mi = 0; mi < 4; ++mi) {
                int v0 = mt * 128 + wm * 64 + mi * 16 + rg;
#pragma unroll
                for (int r = 0; r < 4; ++r)
                    if (v0 + r < VOC) s += expf(acc[mi][ni][r] - lm);
            }
            s += __shfl_xor(s, 16);
            s += __shfl_xor(s, 32);
            if (lane < 16) {
                redm[wm][wn * 64 + ni * 16 + lane] = lm;
                reds[wm][wn * 64 + ni * 16 + lane] = s;
            }
        }
        __syncthreads();
        if (tid < 128) {
            float m0_ = redm[0][tid], m1_ = redm[1][tid];
            float m = fmaxf(m0_, m1_);
            float s = reds[0][tid] * expf(m0_ - m) + reds[1][tid] * expf(m1_ - m);
            int n = nt * 128 + tid;
            q0[(size_t)n * NTMP + mt] = m;
            q3[(size_t)n * NTMP + mt] = s;
        }
    }
}

// ------------------------------------------------- GRU step: LDS-staged h, 128 blocks
__global__ __launch_bounds__(256) void k_gru2(const float* __restrict__ GI,
                                              const float* __restrict__ Whh,
                                              const float* __restrict__ bhh,
                                              const float* __restrict__ h0,
                                              float* __restrict__ Hall, int t) {
    __shared__ float hl[8][1028];
    int jb = blockIdx.x, bg = blockIdx.y;
    int tid = threadIdx.x;
#pragma unroll
    for (int i = 0; i < 8; ++i) {
        int idx = tid + i * 256;
        int brow = idx >> 8, c4 = (idx & 255) * 4;
        int bglob = bg * 8 + brow;
        const float* hp = (t == 0) ? h0 + (size_t)bglob * 1024
                                   : Hall + ((size_t)bglob * 64 + (t - 1)) * 1024;
        *(float4*)&hl[brow][c4] = *(const float4*)(hp + c4);
    }
    __syncthreads();
    int b_loc = tid & 7, jl = tid >> 3;
    int j = jb * 32 + jl;
    int bglob = bg * 8 + b_loc;
    const float4* hr = (const float4*)hl[b_loc];
    const float4* wr = (const float4*)(Whh + (size_t)j * 1024);
    const float4* wz = (const float4*)(Whh + (size_t)(j + 1024) * 1024);
    const float4* wn_ = (const float4*)(Whh + (size_t)(j + 2048) * 1024);
    float ar = 0, az = 0, an = 0;
    for (int kq = 0; kq < 256; ++kq) {
        float4 h = hr[kq];
        ar += dot4(h, wr[kq]); az += dot4(h, wz[kq]); an += dot4(h, wn_[kq]);
    }
    int n = bglob * 64 + t;
    float ir = GI[(size_t)n * 3072 + j];
    float iz = GI[(size_t)n * 3072 + 1024 + j];
    float inn = GI[(size_t)n * 3072 + 2048 + j];
    float r = sigmoidf_(ir + ar + bhh[j]);
    float z = sigmoidf_(iz + az + bhh[1024 + j]);
    float nn = tanhf(inn + r * (an + bhh[2048 + j]));
    Hall[(size_t)n * 1024 + j] = (1.0f - z) * nn + z * hl[b_loc][j];
}

// ------------------------------------------------- per-row lse from partials
__global__ __launch_bounds__(256) void k_lse(const float* __restrict__ pmax,
                                             const float* __restrict__ psum,
                                             float* __restrict__ lse) {
    int n = blockIdx.x;
    int t = threadIdx.x;
    __shared__ float sm[256];
    const float* pm = pmax + (size_t)n * NTMP;
    const float* ps = psum + (size_t)n * NTMP;
    float m = -1e30f;
    for (int p = t; p < NTM; p += 256) m = fmaxf(m, pm[p]);
    sm[t] = m;
    __syncthreads();
    for (int s = 128; s > 0; s >>= 1) { if (t < s) sm[t] = fmaxf(sm[t], sm[t + s]); __syncthreads(); }
    m = sm[0];
    __syncthreads();
    float s = 0.0f;
    for (int p = t; p < NTM; p += 256) s += ps[p] * expf(pm[p] - m);
    sm[t] = s;
    __syncthreads();
    for (int r = 128; r > 0; r >>= 1) { if (t < r) sm[t] += sm[t + r]; __syncthreads(); }
    if (t == 0) lse[n] = m + logf(sm[0]);
}

// ------------------------------------------------- final combine (fully coalesced)
__global__ __launch_bounds__(256) void k_final(const u16* __restrict__ Lb,
                                               const unsigned char* __restrict__ g8,
                                               const float* __restrict__ lse,
                                               const float* __restrict__ ks,
                                               const float* __restrict__ lsek,
                                               float* __restrict__ out) {
    int n = blockIdx.y;
    int b = n >> 6;
    float lsen = lse[n], lkb = lsek[b];
    int base = blockIdx.x * 2048;
#pragma unroll
    for (int i = 0; i < 8; ++i) {
        int v = base + i * 256 + threadIdx.x;
        if (v < VOC) {
            float L = bf2f(Lb[(size_t)n * VOCP + v]);
            float g = g8[(size_t)n * VOCP + v] * (1.0f / 255.0f);
            float kp = ((v >= 10 && v < 10 + KSN) ? ks[(size_t)b * KSN + (v - 10)] : 0.0f) - lkb;
            out[(size_t)n * VOC + v] = g * (L - lsen) + (1.0f - g) * kp;
        }
    }
}

// ---------------------------------------------------------------- launch
extern "C" void kernel_launch(void* const* d_in, const int* in_sizes, int n_in,
                              void* d_out, int out_size, void* d_ws, size_t ws_size,
                              hipStream_t stream) {
    const float* ses    = (const float*)d_in[0];
    const float* know   = (const float*)d_in[1];
    const int*   target = (const int*)d_in[2];
    const float* embed  = (const float*)d_in[3];
    const float* Wih    = (const float*)d_in[4];
    const float* Whh    = (const float*)d_in[5];
    const float* bih    = (const float*)d_in[6];
    const float* bhh    = (const float*)d_in[7];
    const float* sdw    = (const float*)d_in[8];
    const float* sdb    = (const float*)d_in[9];
    const float* dw     = (const float*)d_in[10];
    const float* siw    = (const float*)d_in[11];
    const float* ew     = (const float*)d_in[12];
    const float* eb     = (const float*)d_in[13];
    const float* W1     = (const float*)d_in[14];
    const float* W2     = (const float*)d_in[15];
    const float* W3     = (const float*)d_in[16];
    const float* W4     = (const float*)d_in[17];
    const float* kvw    = (const float*)d_in[18];

    char* ws = (char*)d_ws;
    size_t o = 0;
    auto alloc = [&](size_t bytes) { char* r = ws + o; o += (bytes + 255) & ~(size_t)255; return r; };
    u16*   Aemb  = (u16*)  alloc((size_t)VOCP * 512 * 2);
    u16*   A34   = (u16*)  alloc((size_t)VOCP * 1536 * 2);
    u16*   Adwew = (u16*)  alloc((size_t)1024 * 1536 * 2);
    u16*   Wihb  = (u16*)  alloc((size_t)3072 * 512 * 2);
    u16*   BG    = (u16*)  alloc((size_t)2048 * 1536 * 2);
    u16*   BL    = (u16*)  alloc((size_t)2048 * 512 * 2);
    float* GI    = (float*)alloc((size_t)2048 * 3072 * 4);
    float* Hall  = (float*)alloc((size_t)2048 * 1024 * 4);
    float* h0    = (float*)alloc((size_t)32 * 1024 * 4);
    float* sesinf= (float*)alloc((size_t)32 * 1024 * 4);
    float* gc    = (float*)alloc((size_t)32 * VOCP * 4);
    float* ksb   = (float*)alloc((size_t)32 * KSN * 4);
    float* lsek  = (float*)alloc(256);
    float* lse   = (float*)alloc((size_t)2048 * 4);
    float* pmax  = (float*)alloc((size_t)2048 * NTMP * 4);
    float* psum  = (float*)alloc((size_t)2048 * NTMP * 4);
    unsigned char* g8 = (unsigned char*)alloc((size_t)2048 * VOCP);
    u16*   Lb    = (u16*)  alloc((size_t)2048 * VOCP * 2);
    float* out = (float*)d_out;

    // weight conversions
    k_cvt<<<dim3(VOC, 1), 256, 0, stream>>>(embed, Aemb, 512, 512, 512);
    k_cvt<<<dim3(VOC, 1), 256, 0, stream>>>(W3, A34, 1024, 1024, 1536);
    k_cvt<<<dim3(VOC, 1), 256, 0, stream>>>(W4, A34 + 1024, 512, 512, 1536);
    k_pad0<<<dim3(VOCP - VOC), 256, 0, stream>>>(Aemb, A34);
    k_cvt<<<dim3(1024, 1), 256, 0, stream>>>(dw, Adwew, 1024, 1024, 1536);
    k_cvt<<<dim3(1024, 1), 256, 0, stream>>>(ew, Adwew + 1024, 512, 512, 1536);
    k_cvt<<<dim3(3072, 1), 256, 0, stream>>>(Wih, Wihb, 512, 512, 512);

    k_gather<<<dim3(2048), 128, 0, stream>>>(embed, target, BG);
    k_h0_sesinf<<<dim3(32), 256, 0, stream>>>(ses, sdw, sdb, siw, h0, sesinf);
    k_gateconst<<<dim3(782), 256, 0, stream>>>(ses, know, W1, W2, gc);
    k_ks<<<dim3(275), 256, 0, stream>>>(know, kvw, ksb);
    k_lseknow<<<dim3(32), 256, 0, stream>>>(ksb, lsek);

    // GI = TE @ Wih.T + bih
    gemm_bt<0><<<dim3(16, 24), 256, 0, stream>>>(Wihb, 512, BG + 1024, 1536, 512,
                                                 bih, nullptr, GI, nullptr, nullptr, nullptr);
    // GRU recurrence
    for (int t = 0; t < 64; ++t)
        k_gru2<<<dim3(32, 4), 256, 0, stream>>>(GI, Whh, bhh, h0, Hall, t);
    // Hall -> BG[:,0:1024] bf16
    k_cvt<<<dim3(2048, 1), 256, 0, stream>>>(Hall, BG, 1024, 1024, 1536);
    // MX (maxout) -> BL
    gemm_bt<1><<<dim3(16, 8), 256, 0, stream>>>(Adwew, 1536, BG, 1536, 1536,
                                                sesinf, eb, nullptr, BL, nullptr, nullptr);
    // gate GEMM -> g8
    gemm_bt<2><<<dim3(16, NTM), 256, 0, stream>>>(A34, 1536, BG, 1536, 1536,
                                                  gc, nullptr, nullptr, nullptr, g8, nullptr);
    // logit GEMM -> Lb + partials
    gemm_bt<3><<<dim3(16, NTM), 256, 0, stream>>>(Aemb, 512, BL, 512, 512,
                                                  nullptr, nullptr, pmax, Lb, nullptr, psum);
    k_lse<<<dim3(2048), 256, 0, stream>>>(pmax, psum, lse);
    k_final<<<dim3(25, 2048), 256, 0, stream>>>(Lb, g8, lse, ksb, lsek, out);
}

// Round 3
// 2174.570 us; speedup vs baseline: 7.9335x; 1.6849x over previous
//
#include <hip/hip_runtime.h>

// Problem dims
constexpr int VOC  = 50005;
constexpr int VOCP = 50048;   // 391*128, padded vocab
constexpr int NTM  = 391;     // vocab tiles (128) for big GEMMs
constexpr int NTMP = 400;     // padded partial stride
constexpr int KSN  = 8784;    // KNOW-1
constexpr int KSNP = 8832;    // 69*128
constexpr float NPAD = 41221.0f;

typedef unsigned short u16;
typedef __attribute__((ext_vector_type(4))) float f32x4;
typedef __attribute__((ext_vector_type(8))) short bf16x8;

__device__ __forceinline__ float dot4(float4 a, float4 b) {
    return a.x*b.x + a.y*b.y + a.z*b.z + a.w*b.w;
}
__device__ __forceinline__ float sigmoidf_(float x) { return 1.0f / (1.0f + expf(-x)); }
__device__ __forceinline__ u16 f2bf(float f) {
    unsigned x = __float_as_uint(f);
    return (u16)((x + 0x7FFFu + ((x >> 16) & 1u)) >> 16);
}
__device__ __forceinline__ float bf2f(u16 u) { return __uint_as_float(((unsigned)u) << 16); }
__device__ __forceinline__ void gload_lds16(const void* g, void* l) {
    __builtin_amdgcn_global_load_lds((const __attribute__((address_space(1))) unsigned int*)g,
                                     (__attribute__((address_space(3))) unsigned int*)l, 16, 0, 0);
}

// ---------------------------------------------------------------- cvt fp32 -> bf16 (strided)
__global__ __launch_bounds__(256) void k_cvt(const float* __restrict__ src, u16* __restrict__ dst,
                                             int ncols, int sld, int dld) {
    int row = blockIdx.x;
    int c = (blockIdx.y * 256 + threadIdx.x) * 4;
    if (c >= ncols) return;
    float4 v = *(const float4*)(src + (size_t)row * sld + c);
    unsigned lo = f2bf(v.x) | ((unsigned)f2bf(v.y) << 16);
    unsigned hi = f2bf(v.z) | ((unsigned)f2bf(v.w) << 16);
    *(uint2*)(dst + (size_t)row * dld + c) = make_uint2(lo, hi);
}

// zero pad rows 50005..50047 of Aemb / A34 / Awk
__global__ __launch_bounds__(256) void k_pad0(u16* __restrict__ Aemb, u16* __restrict__ A34,
                                              u16* __restrict__ Awk) {
    int r = VOC + blockIdx.x;
    unsigned* pe = (unsigned*)(Aemb + (size_t)r * 512);
    if (threadIdx.x < 256) pe[threadIdx.x] = 0;
    unsigned* p3 = (unsigned*)(A34 + (size_t)r * 1536);
    for (int i = threadIdx.x; i < 768; i += 256) p3[i] = 0;
    unsigned* pw = (unsigned*)(Awk + (size_t)r * 2048);
    for (int i = threadIdx.x; i < 1024; i += 256) pw[i] = 0;
}
// zero pad rows 8784..8831 of kvwb
__global__ __launch_bounds__(256) void k_padK(u16* __restrict__ kvwb) {
    int r = KSN + blockIdx.x;
    unsigned* p = (unsigned*)(kvwb + (size_t)r * 1024);
    for (int i = threadIdx.x; i < 512; i += 256) p[i] = 0;
}

// build Bsk [128][2048] bf16: rows 0..31 = [ses|know], rows 32..127 = 0
__global__ __launch_bounds__(256) void k_bsk(const float* __restrict__ ses,
                                             const float* __restrict__ know,
                                             u16* __restrict__ Bsk) {
    int row = blockIdx.x;
    for (int c0 = threadIdx.x * 4; c0 < 2048; c0 += 1024) {
        uint2 val = make_uint2(0, 0);
        if (row < 32) {
            const float* srcp = (c0 < 1024) ? ses + (size_t)row * 1024 + c0
                                            : know + (size_t)row * 1024 + (c0 - 1024);
            float4 v = *(const float4*)srcp;
            val = make_uint2(f2bf(v.x) | ((unsigned)f2bf(v.y) << 16),
                             f2bf(v.z) | ((unsigned)f2bf(v.w) << 16));
        }
        *(uint2*)(Bsk + (size_t)row * 2048 + c0) = val;
    }
}

// transpose Whh [3072][1024] -> WhhT [1024][3072]
__global__ __launch_bounds__(256) void k_tr(const float* __restrict__ src, float* __restrict__ dst) {
    __shared__ float t[32][33];
    int r0 = blockIdx.x * 32, c0 = blockIdx.y * 32;
    int tr = threadIdx.x & 31, tc = threadIdx.x >> 5;
    for (int i = 0; i < 32; i += 8)
        t[tc + i][tr] = src[(size_t)(r0 + tc + i) * 1024 + c0 + tr];
    __syncthreads();
    for (int i = 0; i < 32; i += 8)
        dst[(size_t)(c0 + tc + i) * 3072 + r0 + tr] = t[tr][tc + i];
}

// ---------------------------------------------------------------- gather target embeddings -> BG[:,1024:1536] bf16
__global__ __launch_bounds__(128) void k_gather(const float* __restrict__ embed,
                                                const int* __restrict__ target,
                                                u16* __restrict__ BG) {
    int n = blockIdx.x;
    int row = target[n];
    int c = threadIdx.x * 4;
    float4 v = *(const float4*)(embed + (size_t)row * 512 + c);
    unsigned lo = f2bf(v.x) | ((unsigned)f2bf(v.y) << 16);
    unsigned hi = f2bf(v.z) | ((unsigned)f2bf(v.w) << 16);
    *(uint2*)(BG + (size_t)n * 1536 + 1024 + c) = make_uint2(lo, hi);
}

// ------------------------------------------------- h0 + ses_inf_vec (fp32, small)
__global__ __launch_bounds__(256) void k_h0_sesinf(const float* __restrict__ ses,
                                                   const float* __restrict__ sdw,
                                                   const float* __restrict__ sdb,
                                                   const float* __restrict__ siw,
                                                   float* __restrict__ h0,
                                                   float* __restrict__ sesinf) {
    int g = blockIdx.x * 256 + threadIdx.x;
    int b = g & 31;
    int jg = g >> 5;
    int j0 = jg * 4;
    const float4* s4 = (const float4*)(ses + (size_t)b * 1024);
    const float4* wa[4];
    const float4* wc[4];
#pragma unroll
    for (int r = 0; r < 4; ++r) {
        wa[r] = (const float4*)(sdw + (size_t)(j0 + r) * 1024);
        wc[r] = (const float4*)(siw + (size_t)(j0 + r) * 1024);
    }
    float a[4] = {0, 0, 0, 0}, c[4] = {0, 0, 0, 0};
    for (int kq = 0; kq < 256; ++kq) {
        float4 sv = s4[kq];
#pragma unroll
        for (int r = 0; r < 4; ++r) { a[r] += dot4(sv, wa[r][kq]); c[r] += dot4(sv, wc[r][kq]); }
    }
#pragma unroll
    for (int r = 0; r < 4; ++r) {
        h0[b * 1024 + j0 + r] = tanhf(a[r] + sdb[j0 + r]);
        sesinf[b * 1024 + j0 + r] = c[r];
    }
}

// ------------------------------------------------- lse of padded know scores
__global__ __launch_bounds__(256) void k_lseknow(const float* __restrict__ ks,
                                                 float* __restrict__ lsek) {
    int b = blockIdx.x;
    int t = threadIdx.x;
    __shared__ float sm[256];
    float m = -1e30f;
    for (int j = t; j < KSN; j += 256) m = fmaxf(m, ks[(size_t)b * KSN + j]);
    sm[t] = m;
    __syncthreads();
    for (int s = 128; s > 0; s >>= 1) { if (t < s) sm[t] = fmaxf(sm[t], sm[t + s]); __syncthreads(); }
    m = fmaxf(sm[0], 0.0f);
    __syncthreads();
    float s = 0.0f;
    for (int j = t; j < KSN; j += 256) s += expf(ks[(size_t)b * KSN + j] - m);
    sm[t] = s;
    __syncthreads();
    for (int r = 128; r > 0; r >>= 1) { if (t < r) sm[t] += sm[t + r]; __syncthreads(); }
    if (t == 0) lsek[b] = m + logf(sm[0] + NPAD * expf(0.0f - m));
}

// ================================================= templated bf16 MFMA GEMM (C[m][n] = A[m]·B[n])
// EPI 0: GI (+bias, fp32)  EPI 1: MX maxout  EPI 2: gate (u8)  EPI 3: logits+partials
// EPI 4: gc fp32 [b][VOCP] (n<32)  EPI 5: ks fp32 [b][KSN] (n<32, m<KSN)
template<int EPI>
__global__ __launch_bounds__(256) void gemm_bt(
    const u16* __restrict__ A, int lda,
    const u16* __restrict__ B, int ldb, int K,
    const float* __restrict__ p0, const float* __restrict__ p1,
    float* __restrict__ q0, u16* __restrict__ q1,
    unsigned char* __restrict__ q2, float* __restrict__ q3)
{
    __shared__ u16 Asm[128 * 64];
    __shared__ u16 Bsm[128 * 64];
    const int tid = threadIdx.x;
    const int lane = tid & 63;
    const int w = tid >> 6;
    const int wm = w >> 1, wn = w & 1;
    const int nt = blockIdx.x, mt = blockIdx.y;

    f32x4 acc[4][4];
#pragma unroll
    for (int i = 0; i < 4; ++i)
#pragma unroll
        for (int j = 0; j < 4; ++j) acc[i][j] = (f32x4){0.f, 0.f, 0.f, 0.f};

    for (int kt = 0; kt < K; kt += 64) {
#pragma unroll
        for (int p = 0; p < 4; ++p) {
            int flat = (w * 4 + p) * 64 + lane;       // 0..1023 16B-slots
            int row = flat >> 3, slot = flat & 7;
            int ss = slot ^ (row & 7);                // inverse-swizzled source slot
            gload_lds16(A + (size_t)(mt * 128 + row) * lda + kt + ss * 8, Asm + flat * 8);
            gload_lds16(B + (size_t)(nt * 128 + row) * ldb + kt + ss * 8, Bsm + flat * 8);
        }
        __syncthreads();
#pragma unroll
        for (int kc = 0; kc < 2; ++kc) {
            bf16x8 af[4], bfr[4];
#pragma unroll
            for (int mi = 0; mi < 4; ++mi) {
                int row = wm * 64 + mi * 16 + (lane & 15);
                int bcol = kc * 64 + ((lane >> 4) << 4);
                af[mi] = *(const bf16x8*)((const char*)Asm + row * 128 + (bcol ^ ((row & 7) << 4)));
            }
#pragma unroll
            for (int ni = 0; ni < 4; ++ni) {
                int row = wn * 64 + ni * 16 + (lane & 15);
                int bcol = kc * 64 + ((lane >> 4) << 4);
                bfr[ni] = *(const bf16x8*)((const char*)Bsm + row * 128 + (bcol ^ ((row & 7) << 4)));
            }
#pragma unroll
            for (int mi = 0; mi < 4; ++mi)
#pragma unroll
                for (int ni = 0; ni < 4; ++ni)
                    acc[mi][ni] = __builtin_amdgcn_mfma_f32_16x16x32_bf16(af[mi], bfr[ni], acc[mi][ni], 0, 0, 0);
        }
        __syncthreads();
    }

    const int cl = lane & 15;           // n offset within fragment
    const int rg = (lane >> 4) << 2;    // m base within fragment

    if constexpr (EPI == 0) {           // GI = TE@Wih.T + bih  (fp32 [n][3072])
#pragma unroll
        for (int mi = 0; mi < 4; ++mi) {
            int m0 = mt * 128 + wm * 64 + mi * 16 + rg;
            float4 bias = *(const float4*)(p0 + m0);
#pragma unroll
            for (int ni = 0; ni < 4; ++ni) {
                int n = nt * 128 + wn * 64 + ni * 16 + cl;
                float4 v;
                v.x = acc[mi][ni][0] + bias.x; v.y = acc[mi][ni][1] + bias.y;
                v.z = acc[mi][ni][2] + bias.z; v.w = acc[mi][ni][3] + bias.w;
                *(float4*)(q0 + (size_t)n * 3072 + m0) = v;
            }
        }
    }
    if constexpr (EPI == 1) {           // maxout -> BL bf16 [n][512]
#pragma unroll
        for (int mi = 0; mi < 4; ++mi) {
            int m0 = mt * 128 + wm * 64 + mi * 16 + rg;
            float4 eb4 = *(const float4*)(p1 + m0);
#pragma unroll
            for (int ni = 0; ni < 4; ++ni) {
                int n = nt * 128 + wn * 64 + ni * 16 + cl;
                int b = n >> 6;
                float v0 = acc[mi][ni][0] + p0[b * 1024 + m0 + 0] + eb4.x;
                float v1 = acc[mi][ni][1] + p0[b * 1024 + m0 + 1] + eb4.y;
                float v2 = acc[mi][ni][2] + p0[b * 1024 + m0 + 2] + eb4.z;
                float v3 = acc[mi][ni][3] + p0[b * 1024 + m0 + 3] + eb4.w;
                unsigned pk = f2bf(fmaxf(v0, v1)) | ((unsigned)f2bf(fmaxf(v2, v3)) << 16);
                *(unsigned*)(q1 + (size_t)n * 512 + (m0 >> 1)) = pk;
            }
        }
    }
    if constexpr (EPI == 2) {           // gate -> g8 u8 [n][VOCP]
#pragma unroll
        for (int mi = 0; mi < 4; ++mi) {
            int v0 = mt * 128 + wm * 64 + mi * 16 + rg;
#pragma unroll
            for (int ni = 0; ni < 4; ++ni) {
                int n = nt * 128 + wn * 64 + ni * 16 + cl;
                int b = n >> 6;
                float4 gcv = *(const float4*)(p0 + (size_t)b * VOCP + v0);
                unsigned pk = 0;
#pragma unroll
                for (int r = 0; r < 4; ++r) {
                    float garg = acc[mi][ni][r] + ((const float*)&gcv)[r];
                    float gate = 1.0f / (1.0f + expf(-garg));
                    pk |= ((unsigned)(int)(gate * 255.0f + 0.5f)) << (8 * r);
                }
                *(unsigned*)(q2 + (size_t)n * VOCP + v0) = pk;
            }
        }
    }
    if constexpr (EPI == 3) {           // logits -> Lb bf16 [n][VOCP] + partial max/sumexp
        __shared__ float redm[2][128];
        __shared__ float reds[2][128];
#pragma unroll
        for (int mi = 0; mi < 4; ++mi) {
            int v0 = mt * 128 + wm * 64 + mi * 16 + rg;
#pragma unroll
            for (int ni = 0; ni < 4; ++ni) {
                int n = nt * 128 + wn * 64 + ni * 16 + cl;
                unsigned lo = f2bf(acc[mi][ni][0]) | ((unsigned)f2bf(acc[mi][ni][1]) << 16);
                unsigned hi = f2bf(acc[mi][ni][2]) | ((unsigned)f2bf(acc[mi][ni][3]) << 16);
                *(uint2*)(q1 + (size_t)n * VOCP + v0) = make_uint2(lo, hi);
            }
        }
#pragma unroll
        for (int ni = 0; ni < 4; ++ni) {
            float lm = -1e30f;
#pragma unroll
            for (int mi = 0; mi < 4; ++mi) {
                int v0 = mt * 128 + wm * 64 + mi * 16 + rg;
#pragma unroll
                for (int r = 0; r < 4; ++r)
                    if (v0 + r < VOC) lm = fmaxf(lm, acc[mi][ni][r]);
            }
            lm = fmaxf(lm, __shfl_xor(lm, 16));
            lm = fmaxf(lm, __shfl_xor(lm, 32));
            float s = 0.0f;
#pragma unroll
            for (int mi = 0; mi < 4; ++mi) {
                int v0 = mt * 128 + wm * 64 + mi * 16 + rg;
#pragma unroll
                for (int r = 0; r < 4; ++r)
                    if (v0 + r < VOC) s += expf(acc[mi][ni][r] - lm);
            }
            s += __shfl_xor(s, 16);
            s += __shfl_xor(s, 32);
            if (lane < 16) {
                redm[wm][wn * 64 + ni * 16 + lane] = lm;
                reds[wm][wn * 64 + ni * 16 + lane] = s;
            }
        }
        __syncthreads();
        if (tid < 128) {
            float m0_ = redm[0][tid], m1_ = redm[1][tid];
            float m = fmaxf(m0_, m1_);
            float s = reds[0][tid] * expf(m0_ - m) + reds[1][tid] * expf(m1_ - m);
            int n = nt * 128 + tid;
            q0[(size_t)n * NTMP + mt] = m;
            q3[(size_t)n * NTMP + mt] = s;
        }
    }
    if constexpr (EPI == 4) {           // gc fp32 [b][VOCP], only n<32 valid
#pragma unroll
        for (int mi = 0; mi < 4; ++mi) {
            int m0 = mt * 128 + wm * 64 + mi * 16 + rg;
#pragma unroll
            for (int ni = 0; ni < 4; ++ni) {
                int n = nt * 128 + wn * 64 + ni * 16 + cl;
                if (n < 32) {
                    float4 v;
                    v.x = acc[mi][ni][0]; v.y = acc[mi][ni][1];
                    v.z = acc[mi][ni][2]; v.w = acc[mi][ni][3];
                    *(float4*)(q0 + (size_t)n * VOCP + m0) = v;
                }
            }
        }
    }
    if constexpr (EPI == 5) {           // ks fp32 [b][KSN], n<32, m<KSN
#pragma unroll
        for (int mi = 0; mi < 4; ++mi) {
            int m0 = mt * 128 + wm * 64 + mi * 16 + rg;
#pragma unroll
            for (int ni = 0; ni < 4; ++ni) {
                int n = nt * 128 + wn * 64 + ni * 16 + cl;
                if (n < 32 && m0 < KSN) {
                    float4 v;
                    v.x = acc[mi][ni][0]; v.y = acc[mi][ni][1];
                    v.z = acc[mi][ni][2]; v.w = acc[mi][ni][3];
                    *(float4*)(q0 + (size_t)n * KSN + m0) = v;
                }
            }
        }
    }
}

// ------------------------------------------------- GRU phase A: partial h@Whh.T (split-K)
// grid (32 jb, 16 kh), 256 threads = 32 jl x 8 bq (4 b each). fp32 throughout.
__global__ __launch_bounds__(256) void k_gruA(const float* __restrict__ WhhT,
                                              const float* __restrict__ h0,
                                              const float* __restrict__ Hall,
                                              float* __restrict__ psumG, int t) {
    __shared__ float hl[32][68];
    int jb = blockIdx.x, kh = blockIdx.y;
    int tid = threadIdx.x;
#pragma unroll
    for (int p = 0; p < 2; ++p) {
        int id = tid + p * 256;
        int row = id >> 4, c4 = (id & 15) * 4;
        const float* hp = (t == 0) ? h0 + (size_t)row * 1024
                                   : Hall + ((size_t)row * 64 + t - 1) * 1024;
        float4 v = *(const float4*)(hp + kh * 64 + c4);
        hl[row][c4 + 0] = v.x; hl[row][c4 + 1] = v.y;
        hl[row][c4 + 2] = v.z; hl[row][c4 + 3] = v.w;
    }
    __syncthreads();
    int jl = tid & 31, bq = tid >> 5;
    int j = jb * 32 + jl;
    int b0 = bq * 4;
    float acc[3][4] = {{0,0,0,0},{0,0,0,0},{0,0,0,0}};
    const float* wbase = WhhT + (size_t)(kh * 64) * 3072 + j;
    for (int kq = 0; kq < 64; ++kq) {
        float ha = hl[b0 + 0][kq], hb = hl[b0 + 1][kq];
        float hc = hl[b0 + 2][kq], hd = hl[b0 + 3][kq];
        const float* wk = wbase + (size_t)kq * 3072;
#pragma unroll
        for (int g = 0; g < 3; ++g) {
            float wv = wk[g * 1024];
            acc[g][0] += wv * ha; acc[g][1] += wv * hb;
            acc[g][2] += wv * hc; acc[g][3] += wv * hd;
        }
    }
    // psum[kh][g][b][j]
#pragma unroll
    for (int g = 0; g < 3; ++g)
#pragma unroll
        for (int bb = 0; bb < 4; ++bb)
            psumG[(((size_t)kh * 3 + g) * 32 + (b0 + bb)) * 1024 + j] = acc[g][bb];
}

// ------------------------------------------------- GRU phase B: reduce + gate math
__global__ __launch_bounds__(256) void k_gruB(const float* __restrict__ psumG,
                                              const float* __restrict__ GI,
                                              const float* __restrict__ bhh,
                                              const float* __restrict__ h0,
                                              float* __restrict__ Hall, int t) {
    int gid = blockIdx.x * 256 + threadIdx.x;  // 32768
    int b = gid >> 10, j = gid & 1023;
    float s0 = 0, s1 = 0, s2 = 0;
#pragma unroll
    for (int kh = 0; kh < 16; ++kh) {
        size_t base = (size_t)kh * 3 * 32 * 1024;
        s0 += psumG[base + (size_t)(0 * 32 + b) * 1024 + j];
        s1 += psumG[base + (size_t)(1 * 32 + b) * 1024 + j];
        s2 += psumG[base + (size_t)(2 * 32 + b) * 1024 + j];
    }
    float hprev = (t == 0) ? h0[(size_t)b * 1024 + j] : Hall[((size_t)b * 64 + t - 1) * 1024 + j];
    int n = b * 64 + t;
    float r = sigmoidf_(GI[(size_t)n * 3072 + j] + s0 + bhh[j]);
    float z = sigmoidf_(GI[(size_t)n * 3072 + 1024 + j] + s1 + bhh[1024 + j]);
    float nn = tanhf(GI[(size_t)n * 3072 + 2048 + j] + r * (s2 + bhh[2048 + j]));
    Hall[(size_t)n * 1024 + j] = (1.0f - z) * nn + z * hprev;
}

// ------------------------------------------------- per-row lse from partials
__global__ __launch_bounds__(256) void k_lse(const float* __restrict__ pmax,
                                             const float* __restrict__ psum,
                                             float* __restrict__ lse) {
    int n = blockIdx.x;
    int t = threadIdx.x;
    __shared__ float sm[256];
    const float* pm = pmax + (size_t)n * NTMP;
    const float* ps = psum + (size_t)n * NTMP;
    float m = -1e30f;
    for (int p = t; p < NTM; p += 256) m = fmaxf(m, pm[p]);
    sm[t] = m;
    __syncthreads();
    for (int s = 128; s > 0; s >>= 1) { if (t < s) sm[t] = fmaxf(sm[t], sm[t + s]); __syncthreads(); }
    m = sm[0];
    __syncthreads();
    float s = 0.0f;
    for (int p = t; p < NTM; p += 256) s += ps[p] * expf(pm[p] - m);
    sm[t] = s;
    __syncthreads();
    for (int r = 128; r > 0; r >>= 1) { if (t < r) sm[t] += sm[t + r]; __syncthreads(); }
    if (t == 0) lse[n] = m + logf(sm[0]);
}

// ------------------------------------------------- final combine (fully coalesced)
__global__ __launch_bounds__(256) void k_final(const u16* __restrict__ Lb,
                                               const unsigned char* __restrict__ g8,
                                               const float* __restrict__ lse,
                                               const float* __restrict__ ks,
                                               const float* __restrict__ lsek,
                                               float* __restrict__ out) {
    int n = blockIdx.y;
    int b = n >> 6;
    float lsen = lse[n], lkb = lsek[b];
    int base = blockIdx.x * 2048;
#pragma unroll
    for (int i = 0; i < 8; ++i) {
        int v = base + i * 256 + threadIdx.x;
        if (v < VOC) {
            float L = bf2f(Lb[(size_t)n * VOCP + v]);
            float g = g8[(size_t)n * VOCP + v] * (1.0f / 255.0f);
            float kp = ((v >= 10 && v < 10 + KSN) ? ks[(size_t)b * KSN + (v - 10)] : 0.0f) - lkb;
            out[(size_t)n * VOC + v] = g * (L - lsen) + (1.0f - g) * kp;
        }
    }
}

// ---------------------------------------------------------------- launch
extern "C" void kernel_launch(void* const* d_in, const int* in_sizes, int n_in,
                              void* d_out, int out_size, void* d_ws, size_t ws_size,
                              hipStream_t stream) {
    const float* ses    = (const float*)d_in[0];
    const float* know   = (const float*)d_in[1];
    const int*   target = (const int*)d_in[2];
    const float* embed  = (const float*)d_in[3];
    const float* Wih    = (const float*)d_in[4];
    const float* Whh    = (const float*)d_in[5];
    const float* bih    = (const float*)d_in[6];
    const float* bhh    = (const float*)d_in[7];
    const float* sdw    = (const float*)d_in[8];
    const float* sdb    = (const float*)d_in[9];
    const float* dw     = (const float*)d_in[10];
    const float* siw    = (const float*)d_in[11];
    const float* ew     = (const float*)d_in[12];
    const float* eb     = (const float*)d_in[13];
    const float* W1     = (const float*)d_in[14];
    const float* W2     = (const float*)d_in[15];
    const float* W3     = (const float*)d_in[16];
    const float* W4     = (const float*)d_in[17];
    const float* kvw    = (const float*)d_in[18];

    char* ws = (char*)d_ws;
    size_t o = 0;
    auto alloc = [&](size_t bytes) { char* r = ws + o; o += (bytes + 255) & ~(size_t)255; return r; };
    u16*   Aemb  = (u16*)  alloc((size_t)VOCP * 512 * 2);
    u16*   A34   = (u16*)  alloc((size_t)VOCP * 1536 * 2);
    u16*   Adwew = (u16*)  alloc((size_t)1024 * 1536 * 2);
    u16*   Wihb  = (u16*)  alloc((size_t)3072 * 512 * 2);
    u16*   BG    = (u16*)  alloc((size_t)2048 * 1536 * 2);
    u16*   BL    = (u16*)  alloc((size_t)2048 * 512 * 2);
    float* GI    = (float*)alloc((size_t)2048 * 3072 * 4);
    float* Hall  = (float*)alloc((size_t)2048 * 1024 * 4);
    float* WhhT  = (float*)alloc((size_t)1024 * 3072 * 4);
    float* h0    = (float*)alloc((size_t)32 * 1024 * 4);
    float* sesinf= (float*)alloc((size_t)32 * 1024 * 4);
    float* gc    = (float*)alloc((size_t)32 * VOCP * 4);
    float* ksb   = (float*)alloc((size_t)32 * KSN * 4);
    float* lsek  = (float*)alloc(256);
    float* lse   = (float*)alloc((size_t)2048 * 4);
    float* pmax  = (float*)alloc((size_t)2048 * NTMP * 4);   // aliased: psumG spans pmax+psum
    float* psum  = (float*)alloc((size_t)2048 * NTMP * 4);
    unsigned char* g8 = (unsigned char*)alloc((size_t)2048 * VOCP);   // aliased: kvwb
    u16*   Lb    = (u16*)  alloc((size_t)2048 * VOCP * 2);            // aliased: Awk
    u16*   Bsk   = (u16*)  alloc((size_t)128 * 2048 * 2);
    float* out = (float*)d_out;

    float* psumG = pmax;           // 16*3*32*1024*4 = 6.29 MB <= pmax+psum (6.55 MB)
    u16*   kvwb  = (u16*)g8;       // 8832*1024*2 = 18.1 MB <= g8 (102 MB)
    u16*   Awk   = Lb;             // 50048*2048*2 == Lb size

    // weight conversions (early users of aliased buffers come first)
    k_cvt<<<dim3(VOC, 1), 256, 0, stream>>>(embed, Aemb, 512, 512, 512);
    k_cvt<<<dim3(VOC, 1), 256, 0, stream>>>(W3, A34, 1024, 1024, 1536);
    k_cvt<<<dim3(VOC, 1), 256, 0, stream>>>(W4, A34 + 1024, 512, 512, 1536);
    k_cvt<<<dim3(VOC, 1), 256, 0, stream>>>(W1, Awk, 1024, 1024, 2048);
    k_cvt<<<dim3(VOC, 1), 256, 0, stream>>>(W2, Awk + 1024, 1024, 1024, 2048);
    k_cvt<<<dim3(KSN, 1), 256, 0, stream>>>(kvw, kvwb, 1024, 1024, 1024);
    k_pad0<<<dim3(VOCP - VOC), 256, 0, stream>>>(Aemb, A34, Awk);
    k_padK<<<dim3(KSNP - KSN), 256, 0, stream>>>(kvwb);
    k_cvt<<<dim3(1024, 1), 256, 0, stream>>>(dw, Adwew, 1024, 1024, 1536);
    k_cvt<<<dim3(1024, 1), 256, 0, stream>>>(ew, Adwew + 1024, 512, 512, 1536);
    k_cvt<<<dim3(3072, 1), 256, 0, stream>>>(Wih, Wihb, 512, 512, 512);
    k_bsk<<<dim3(128), 256, 0, stream>>>(ses, know, Bsk);
    k_tr<<<dim3(96, 32), 256, 0, stream>>>(Whh, WhhT);

    k_gather<<<dim3(2048), 128, 0, stream>>>(embed, target, BG);
    k_h0_sesinf<<<dim3(32), 256, 0, stream>>>(ses, sdw, sdb, siw, h0, sesinf);

    // gc = [W1|W2] @ [ses|know]   (MFMA, n<32 valid)
    gemm_bt<4><<<dim3(1, NTM), 256, 0, stream>>>(Awk, 2048, Bsk, 2048, 2048,
                                                 nullptr, nullptr, gc, nullptr, nullptr, nullptr);
    // ks = kvw @ know   (MFMA, B = know half of Bsk)
    gemm_bt<5><<<dim3(1, 69), 256, 0, stream>>>(kvwb, 1024, Bsk + 1024, 2048, 1024,
                                                nullptr, nullptr, ksb, nullptr, nullptr, nullptr);
    k_lseknow<<<dim3(32), 256, 0, stream>>>(ksb, lsek);

    // GI = TE @ Wih.T + bih
    gemm_bt<0><<<dim3(16, 24), 256, 0, stream>>>(Wihb, 512, BG + 1024, 1536, 512,
                                                 bih, nullptr, GI, nullptr, nullptr, nullptr);
    // GRU recurrence: split-K phase A + reduce phase B
    for (int t = 0; t < 64; ++t) {
        k_gruA<<<dim3(32, 16), 256, 0, stream>>>(WhhT, h0, Hall, psumG, t);
        k_gruB<<<dim3(128), 256, 0, stream>>>(psumG, GI, bhh, h0, Hall, t);
    }
    // Hall -> BG[:,0:1024] bf16
    k_cvt<<<dim3(2048, 1), 256, 0, stream>>>(Hall, BG, 1024, 1024, 1536);
    // MX (maxout) -> BL
    gemm_bt<1><<<dim3(16, 8), 256, 0, stream>>>(Adwew, 1536, BG, 1536, 1536,
                                                sesinf, eb, nullptr, BL, nullptr, nullptr);
    // gate GEMM -> g8
    gemm_bt<2><<<dim3(16, NTM), 256, 0, stream>>>(A34, 1536, BG, 1536, 1536,
                                                  gc, nullptr, nullptr, nullptr, g8, nullptr);
    // logit GEMM -> Lb + partials
    gemm_bt<3><<<dim3(16, NTM), 256, 0, stream>>>(Aemb, 512, BL, 512, 512,
                                                  nullptr, nullptr, pmax, Lb, nullptr, psum);
    k_lse<<<dim3(2048), 256, 0, stream>>>(pmax, psum, lse);
    k_final<<<dim3(25, 2048), 256, 0, stream>>>(Lb, g8, lse, ksb, lsek, out);
}